// Round 5
// baseline (1052.222 us; speedup 1.0000x reference)
//
#include <hip/hip_runtime.h>
#include <math.h>

// ---------------------------------------------------------------------------
// GAT x3 + BN on MI355X.
//   setup:  hist(dst) -> 3-phase parallel scan -> counting-sort edges (CSR).
//   layer:  P = We@a_edge + self logit
//           k_gemm2: h = BN(X)@W (W in LDS, 4x4 reg tile), writes h as BF16,
//                    fused al_s/al_d/es epilogue
//           k_alpha3: meta[e] = {src, p=exp(lrelu(als+ald+ale))}  (8 B packed)
//           k_agg5: one wave per node; per-64-edge window the meta is loaded
//                   coalesced into lane registers, then __shfl-broadcast;
//                   half-wave 0/1 gather DIFFERENT edges (2 edges per VMEM
//                   instr, 8-deep burst = 16 in flight); halves combined via
//                   shfl_xor(32).  No scalar-load serialization, no serial
//                   remainder.  + bias + lrelu + BN partials.
//           k_bnfinal -> scale/shift consumed by NEXT layer's gemm staging;
//           k_bnapply only for the final output.
// R5: R4 showed k_agg latency-bound (VALU 8%, FETCH halved but time -15%):
// kill the srcs->gather dependency + serial remainder, double edges/instr.
// ---------------------------------------------------------------------------

struct __align__(16) Edge { int src; float e0, e1, e2; };

__device__ __forceinline__ unsigned short f2bf(float x) {
  unsigned u = __float_as_uint(x);
  unsigned r = (u + 0x7FFFu + ((u >> 16) & 1u)) >> 16;  // RNE
  return (unsigned short)r;
}
__device__ __forceinline__ float bf_lo(unsigned u) { return __uint_as_float(u << 16); }
__device__ __forceinline__ float bf_hi(unsigned u) { return __uint_as_float(u & 0xFFFF0000u); }

__global__ void k_hist(const int* __restrict__ dst, int E, int* __restrict__ deg) {
  int i = blockIdx.x * blockDim.x + threadIdx.x;
  if (i < E) atomicAdd(&deg[dst[i]], 1);
}

__global__ void k_ea_sum(const float* __restrict__ ea, int E, float* __restrict__ ea_sum) {
  float s0 = 0.f, s1 = 0.f, s2 = 0.f;
  for (int i = blockIdx.x * blockDim.x + threadIdx.x; i < E; i += gridDim.x * blockDim.x) {
    s0 += ea[i * 3 + 0]; s1 += ea[i * 3 + 1]; s2 += ea[i * 3 + 2];
  }
  for (int off = 32; off; off >>= 1) {
    s0 += __shfl_down(s0, off); s1 += __shfl_down(s1, off); s2 += __shfl_down(s2, off);
  }
  __shared__ float ls[3][4];
  int lane = threadIdx.x & 63, w = threadIdx.x >> 6;
  if (lane == 0) { ls[0][w] = s0; ls[1][w] = s1; ls[2][w] = s2; }
  __syncthreads();
  if (threadIdx.x == 0) {
    float t0 = 0.f, t1 = 0.f, t2 = 0.f;
    for (int ww = 0; ww < 4; ++ww) { t0 += ls[0][ww]; t1 += ls[1][ww]; t2 += ls[2][ww]; }
    atomicAdd(&ea_sum[0], t0); atomicAdd(&ea_sum[1], t1); atomicAdd(&ea_sum[2], t2);
  }
}

__device__ __forceinline__ int wave_incl_scan(int x, int lane) {
  for (int off = 1; off < 64; off <<= 1) {
    int t = __shfl_up(x, off);
    if (lane >= off) x += t;
  }
  return x;
}

__global__ __launch_bounds__(1024) void k_scan_a(const int* __restrict__ deg, int n,
                                                 int* __restrict__ start,
                                                 int* __restrict__ bsum) {
  __shared__ int wsum[16];
  int t = threadIdx.x, lane = t & 63, w = t >> 6;
  int i = blockIdx.x * 1024 + t;
  int v = (i < n) ? deg[i] : 0;
  int x = wave_incl_scan(v, lane);
  if (lane == 63) wsum[w] = x;
  __syncthreads();
  if (w == 0 && lane < 16) {
    int s = wsum[lane];
    for (int off = 1; off < 16; off <<= 1) {
      int u = __shfl_up(s, off);
      if (lane >= off) s += u;
    }
    wsum[lane] = s;
  }
  __syncthreads();
  int woff = w ? wsum[w - 1] : 0;
  if (i < n) start[i] = x - v + woff;
  if (t == 1023) bsum[blockIdx.x] = wsum[15];
}

__global__ void k_scan_b(int* __restrict__ bsum, int nb, int* __restrict__ start, int n) {
  int lane = threadIdx.x;  // 64
  int v = (lane < nb) ? bsum[lane] : 0;
  int x = wave_incl_scan(v, lane);
  if (lane < nb) bsum[lane] = x - v;
  if (lane == nb - 1) start[n] = x;
}

__global__ void k_scan_c(int* __restrict__ start, const int* __restrict__ bsum, int n,
                         int* __restrict__ cursor) {
  int i = blockIdx.x * blockDim.x + threadIdx.x;
  if (i < n) {
    int s = start[i] + bsum[i >> 10];
    start[i] = s;
    cursor[i] = s;
  }
}

__global__ void k_scatter(const int* __restrict__ src, const int* __restrict__ dst,
                          const float* __restrict__ ea, int E,
                          int* __restrict__ cursor, Edge* __restrict__ edges,
                          int* __restrict__ dsts) {
  int i = blockIdx.x * blockDim.x + threadIdx.x;
  if (i >= E) return;
  int d = dst[i];
  int pos = atomicAdd(&cursor[d], 1);
  Edge e;
  e.src = src[i];
  e.e0 = ea[i * 3 + 0]; e.e1 = ea[i * 3 + 1]; e.e2 = ea[i * 3 + 2];
  edges[pos] = e;
  dsts[pos] = d;
}

__global__ void k_initid(float* __restrict__ sc, float* __restrict__ sh) {
  int c = threadIdx.x;  // 128
  sc[c] = 1.f; sh[c] = 0.f;
}

__global__ void k_param(const float* __restrict__ We, const float* __restrict__ ae,
                        const float* __restrict__ ea_sum, float invE, float* __restrict__ P) {
  int lane = threadIdx.x;  // 64
  float a0 = ae[lane], a1 = ae[64 + lane];
  float p0 = We[0 * 128 + lane] * a0 + We[0 * 128 + 64 + lane] * a1;
  float p1 = We[1 * 128 + lane] * a0 + We[1 * 128 + 64 + lane] * a1;
  float p2 = We[2 * 128 + lane] * a0 + We[2 * 128 + 64 + lane] * a1;
  for (int off = 32; off; off >>= 1) {
    p0 += __shfl_down(p0, off); p1 += __shfl_down(p1, off); p2 += __shfl_down(p2, off);
  }
  if (lane == 0) {
    P[0] = p0; P[1] = p1; P[2] = p2;
    P[3] = ea_sum[0] * invE * p0 + ea_sum[1] * invE * p1 + ea_sum[2] * invE * p2;
  }
}

// h[N,128] = (X*bnsc+bnsh) @ W, stored as bf16 rows (256 B).  W in LDS,
// 32-row tiles, 4 rows x 4 cols per thread.  Fused al_s/al_d/es epilogue.
__global__ __launch_bounds__(256) void k_gemm2(
    const float* __restrict__ X, const float* __restrict__ Wm,
    const float* __restrict__ bnsc, const float* __restrict__ bnsh,
    const float* __restrict__ as, const float* __restrict__ ad,
    const float* __restrict__ P,
    unsigned* __restrict__ hb, float* __restrict__ al_s, float* __restrict__ al_d,
    float* __restrict__ es, int n) {
  __shared__ float wl[128 * 128];
  __shared__ float xs[32 * 128];
  int t = threadIdx.x;
  for (int i = t; i < 4096; i += 256) ((float4*)wl)[i] = ((const float4*)Wm)[i];
  int c32 = t & 31;
  int c4 = c32 << 2;
  int rq = t >> 5;
  int lane = t & 63;
  float4 av_s = *(const float4*)(as + c4);
  float4 av_d = *(const float4*)(ad + c4);
  float cself = P[3];
  int ntiles = (n + 31) >> 5;
  for (int tile = blockIdx.x; tile < ntiles; tile += gridDim.x) {
    int r0 = tile << 5;
    __syncthreads();
    for (int i = t; i < 1024; i += 256) {
      int rr = i >> 5, cc = i & 31;
      int g = r0 + rr;
      float4 v;
      if (g < n) {
        v = ((const float4*)(X + (size_t)g * 128))[cc];
        float4 sc = ((const float4*)bnsc)[cc];
        float4 sh = ((const float4*)bnsh)[cc];
        v.x = fmaf(v.x, sc.x, sh.x); v.y = fmaf(v.y, sc.y, sh.y);
        v.z = fmaf(v.z, sc.z, sh.z); v.w = fmaf(v.w, sc.w, sh.w);
      } else { v.x = v.y = v.z = v.w = 0.f; }
      ((float4*)xs)[i] = v;
    }
    __syncthreads();
    float4 acc[4];
    for (int r = 0; r < 4; ++r) { acc[r].x = acc[r].y = acc[r].z = acc[r].w = 0.f; }
    const float* xr = xs + (rq << 2) * 128;
#pragma unroll 4
    for (int k = 0; k < 128; ++k) {
      float4 w4 = ((const float4*)wl)[(k << 5) + c32];
#pragma unroll
      for (int r = 0; r < 4; ++r) {
        float xv = xr[r * 128 + k];
        acc[r].x = fmaf(xv, w4.x, acc[r].x);
        acc[r].y = fmaf(xv, w4.y, acc[r].y);
        acc[r].z = fmaf(xv, w4.z, acc[r].z);
        acc[r].w = fmaf(xv, w4.w, acc[r].w);
      }
    }
    int gbase = r0 + (rq << 2);
#pragma unroll
    for (int r = 0; r < 4; ++r) {
      int g = gbase + r;
      float4 o = acc[r];
      if (g < n) {
        unsigned u01 = ((unsigned)f2bf(o.y) << 16) | (unsigned)f2bf(o.x);
        unsigned u23 = ((unsigned)f2bf(o.w) << 16) | (unsigned)f2bf(o.z);
        uint2 uu = {u01, u23};
        *(uint2*)(hb + (size_t)g * 64 + (c32 << 1)) = uu;
      }
      float ps = o.x * av_s.x + o.y * av_s.y + o.z * av_s.z + o.w * av_s.w;
      float pd = o.x * av_d.x + o.y * av_d.y + o.z * av_d.z + o.w * av_d.w;
      for (int off = 16; off; off >>= 1) {
        ps += __shfl_xor(ps, off);
        pd += __shfl_xor(pd, off);
      }
      if ((lane & 31) == 0 && g < n) {
        al_s[g] = ps; al_d[g] = pd;
        float a = ps + pd + cself;
        a = a > 0.f ? a : 0.2f * a;
        es[g] = __expf(a);
      }
    }
  }
}

// meta[e] = {src, p=exp(lrelu_0.2(al_s[src]+al_d[dst]+ea.We@ae))}
__global__ __launch_bounds__(256) void k_alpha3(const float4* __restrict__ edges,
                                                const int* __restrict__ dsts,
                                                const float* __restrict__ al_s,
                                                const float* __restrict__ al_d,
                                                const float* __restrict__ P,
                                                uint2* __restrict__ meta, int E) {
  int i = blockIdx.x * blockDim.x + threadIdx.x;
  if (i >= E) return;
  float4 ef = edges[i];
  int s = __float_as_int(ef.x);
  float a = al_s[s] + al_d[dsts[i]] + ef.y * P[0] + ef.z * P[1] + ef.w * P[2];
  a = a > 0.f ? a : 0.2f * a;
  uint2 m = {(unsigned)s, __float_as_uint(__expf(a))};
  meta[i] = m;
}

// one wave per node.  Meta coalesced into lane regs per 64-edge window, shfl
// broadcast per group; half-waves gather DIFFERENT edges (2/instr, 8-deep
// burst = 16 gathers in flight).  Combine halves via shfl_xor(32).
__global__ __launch_bounds__(256) void k_agg5(const uint2* __restrict__ meta,
                                              const int* __restrict__ start,
                                              const uint2* __restrict__ hb2,
                                              const float* __restrict__ es,
                                              const float* __restrict__ bias,
                                              float* __restrict__ y,
                                              float* __restrict__ colsum,
                                              float* __restrict__ colsumsq, int n) {
  int lane = threadIdx.x & 63;
  int w = threadIdx.x >> 6;
  int half = lane >> 5;   // which edge of the pair this lane gathers
  int hl = lane & 31;     // feature quad: features 4*hl .. 4*hl+3
  int gw = (blockIdx.x * blockDim.x + threadIdx.x) >> 6;
  int nw = (gridDim.x * blockDim.x) >> 6;
  float4 b4 = ((const float4*)bias)[hl];
  float s0 = 0.f, s1 = 0.f, s2 = 0.f, s3 = 0.f;
  float q0 = 0.f, q1 = 0.f, q2 = 0.f, q3 = 0.f;
  for (int i = gw; i < n; i += nw) {
    int e0 = start[i];
    int e1 = start[i + 1];
    float eself = es[i];
    uint2 sv = hb2[(size_t)i * 32 + hl];
    float pself = (half == 0) ? eself : 0.f;
    float a0 = pself * bf_lo(sv.x), a1 = pself * bf_hi(sv.x);
    float a2 = pself * bf_lo(sv.y), a3 = pself * bf_hi(sv.y);
    float pacc = pself;
    for (int wb = e0; wb < e1; wb += 64) {
      int wcount = e1 - wb; if (wcount > 64) wcount = 64;
      uint2 m;
      if (lane < wcount) m = meta[wb + lane];
      else { m.x = 0u; m.y = 0u; }
      int mx = (int)m.x;
      float mp = __uint_as_float(m.y);
      int rounds = (wcount + 15) >> 4;  // bursts of 8 groups x 2 edges
      for (int r = 0; r < rounds; ++r) {
        int gb = r << 3;
        int sl[8]; float pl[8]; uint2 gv[8];
#pragma unroll
        for (int k = 0; k < 8; ++k) {
          int srcLane = ((gb + k) << 1) + half;
          sl[k] = __shfl(mx, srcLane);
          pl[k] = __shfl(mp, srcLane);
        }
#pragma unroll
        for (int k = 0; k < 8; ++k) gv[k] = hb2[(size_t)sl[k] * 32 + hl];
#pragma unroll
        for (int k = 0; k < 8; ++k) {
          float pk = pl[k];
          pacc += pk;
          a0 = fmaf(pk, bf_lo(gv[k].x), a0);
          a1 = fmaf(pk, bf_hi(gv[k].x), a1);
          a2 = fmaf(pk, bf_lo(gv[k].y), a2);
          a3 = fmaf(pk, bf_hi(gv[k].y), a3);
        }
      }
    }
    // combine the two half-waves (feature quads align across halves)
    a0 += __shfl_xor(a0, 32); a1 += __shfl_xor(a1, 32);
    a2 += __shfl_xor(a2, 32); a3 += __shfl_xor(a3, 32);
    pacc += __shfl_xor(pacc, 32);
    float inv = 1.0f / (pacc + 1e-16f);
    float o0 = fmaf(a0, inv, b4.x);
    float o1 = fmaf(a1, inv, b4.y);
    float o2 = fmaf(a2, inv, b4.z);
    float o3 = fmaf(a3, inv, b4.w);
    o0 = o0 > 0.f ? o0 : 0.01f * o0;
    o1 = o1 > 0.f ? o1 : 0.01f * o1;
    o2 = o2 > 0.f ? o2 : 0.01f * o2;
    o3 = o3 > 0.f ? o3 : 0.01f * o3;
    if (half == 0) {
      float4 ov = {o0, o1, o2, o3};
      *(float4*)(y + (size_t)i * 128 + (hl << 2)) = ov;
      s0 += o0; s1 += o1; s2 += o2; s3 += o3;
      q0 = fmaf(o0, o0, q0); q1 = fmaf(o1, o1, q1);
      q2 = fmaf(o2, o2, q2); q3 = fmaf(o3, o3, q3);
    }
  }
  __shared__ float redS[4][32][4];
  __shared__ float redQ[4][32][4];
  if (half == 0) {
    redS[w][hl][0] = s0; redS[w][hl][1] = s1; redS[w][hl][2] = s2; redS[w][hl][3] = s3;
    redQ[w][hl][0] = q0; redQ[w][hl][1] = q1; redQ[w][hl][2] = q2; redQ[w][hl][3] = q3;
  }
  __syncthreads();
  if (w == 0 && half == 0) {
    for (int ww = 1; ww < 4; ++ww) {
      s0 += redS[ww][hl][0]; s1 += redS[ww][hl][1];
      s2 += redS[ww][hl][2]; s3 += redS[ww][hl][3];
      q0 += redQ[ww][hl][0]; q1 += redQ[ww][hl][1];
      q2 += redQ[ww][hl][2]; q3 += redQ[ww][hl][3];
    }
    int f = hl << 2;
    atomicAdd(&colsum[f + 0], s0); atomicAdd(&colsum[f + 1], s1);
    atomicAdd(&colsum[f + 2], s2); atomicAdd(&colsum[f + 3], s3);
    atomicAdd(&colsumsq[f + 0], q0); atomicAdd(&colsumsq[f + 1], q1);
    atomicAdd(&colsumsq[f + 2], q2); atomicAdd(&colsumsq[f + 3], q3);
  }
}

__global__ void k_bnfinal(const float* __restrict__ colsum, const float* __restrict__ colsumsq,
                          const float* __restrict__ g, const float* __restrict__ be,
                          float invN, float* __restrict__ scale, float* __restrict__ shift) {
  int c = threadIdx.x;  // 128
  float mu = colsum[c] * invN;
  float var = colsumsq[c] * invN - mu * mu;
  var = var > 0.f ? var : 0.f;
  float sc = g[c] * rsqrtf(var + 1e-5f);
  scale[c] = sc;
  shift[c] = be[c] - mu * sc;
}

__global__ void k_bnapply(const float4* __restrict__ yin, const float* __restrict__ scale,
                          const float* __restrict__ shift, float4* __restrict__ yout, int total4) {
  int i = blockIdx.x * blockDim.x + threadIdx.x;
  if (i >= total4) return;
  int c4 = i & 31;
  float4 v = yin[i];
  float4 sc = ((const float4*)scale)[c4];
  float4 sh = ((const float4*)shift)[c4];
  v.x = fmaf(v.x, sc.x, sh.x);
  v.y = fmaf(v.y, sc.y, sh.y);
  v.z = fmaf(v.z, sc.z, sh.z);
  v.w = fmaf(v.w, sc.w, sh.w);
  yout[i] = v;
}

extern "C" void kernel_launch(void* const* d_in, const int* in_sizes, int n_in,
                              void* d_out, int out_size, void* d_ws, size_t ws_size,
                              hipStream_t stream) {
  const float* x = (const float*)d_in[0];
  const int* eidx = (const int*)d_in[1];
  const float* ea = (const float*)d_in[3];
  const int H = 128;
  const int N = in_sizes[0] / H;
  const int E = in_sizes[1] / 2;
  const int* srcIdx = eidx;
  const int* dstIdx = eidx + E;

  char* ws = (char*)d_ws;
  size_t off = 0;
  auto alloc = [&](size_t bytes) -> void* {
    void* p = ws + off;
    off = (off + bytes + 255) & ~(size_t)255;
    return p;
  };
  Edge* edges = (Edge*)alloc((size_t)E * sizeof(Edge));
  int* dsts = (int*)alloc((size_t)E * sizeof(int));
  uint2* meta = (uint2*)alloc((size_t)E * sizeof(uint2));
  unsigned* hb = (unsigned*)alloc((size_t)N * 64 * sizeof(unsigned));  // bf16 h
  float* y = (float*)alloc((size_t)N * H * sizeof(float));
  float* al_s = (float*)alloc((size_t)N * sizeof(float));
  float* al_d = (float*)alloc((size_t)N * sizeof(float));
  float* es = (float*)alloc((size_t)N * sizeof(float));
  int* deg = (int*)alloc((size_t)N * sizeof(int));
  int* start = (int*)alloc((size_t)(N + 1) * sizeof(int));
  int* cursor = (int*)alloc((size_t)N * sizeof(int));
  int* bsum = (int*)alloc(64 * sizeof(int));
  float* colstats = (float*)alloc(256 * sizeof(float));
  float* colsum = colstats;
  float* colsumsq = colstats + 128;
  float* scale = (float*)alloc(128 * sizeof(float));
  float* shift = (float*)alloc(128 * sizeof(float));
  float* ea_sum = (float*)alloc(16 * sizeof(float));
  float* P = (float*)alloc(16 * sizeof(float));

  const int nb = (N + 1023) / 1024;  // <= 64

  // ---- setup: sort edges by destination (CSR) ----
  hipMemsetAsync(deg, 0, (size_t)N * sizeof(int), stream);
  hipMemsetAsync(ea_sum, 0, 16 * sizeof(float), stream);
  k_hist<<<(E + 255) / 256, 256, 0, stream>>>(dstIdx, E, deg);
  k_ea_sum<<<256, 256, 0, stream>>>(ea, E, ea_sum);
  k_scan_a<<<nb, 1024, 0, stream>>>(deg, N, start, bsum);
  k_scan_b<<<1, 64, 0, stream>>>(bsum, nb, start, N);
  k_scan_c<<<(N + 255) / 256, 256, 0, stream>>>(start, bsum, N, cursor);
  k_scatter<<<(E + 255) / 256, 256, 0, stream>>>(srcIdx, dstIdx, ea, E, cursor, edges, dsts);
  k_initid<<<1, 128, 0, stream>>>(scale, shift);

  const float* X = x;
  for (int l = 0; l < 3; ++l) {
    const float* W = (const float*)d_in[4 + 8 * l + 0];
    const float* as = (const float*)d_in[4 + 8 * l + 1];
    const float* ad = (const float*)d_in[4 + 8 * l + 2];
    const float* We = (const float*)d_in[4 + 8 * l + 3];
    const float* ae = (const float*)d_in[4 + 8 * l + 4];
    const float* b = (const float*)d_in[4 + 8 * l + 5];
    const float* g = (const float*)d_in[4 + 8 * l + 6];
    const float* be = (const float*)d_in[4 + 8 * l + 7];

    hipMemsetAsync(colstats, 0, 256 * sizeof(float), stream);
    k_param<<<1, 64, 0, stream>>>(We, ae, ea_sum, 1.0f / (float)E, P);
    k_gemm2<<<512, 256, 0, stream>>>(X, W, scale, shift, as, ad, P, hb, al_s, al_d, es, N);
    k_alpha3<<<(E + 255) / 256, 256, 0, stream>>>((const float4*)edges, dsts, al_s, al_d, P,
                                                  meta, E);
    k_agg5<<<2048, 256, 0, stream>>>(meta, start, (const uint2*)hb, es, b, y,
                                     colsum, colsumsq, N);
    k_bnfinal<<<1, 128, 0, stream>>>(colsum, colsumsq, g, be, 1.0f / (float)N, scale, shift);
    X = y;
  }
  k_bnapply<<<((N * 32) + 255) / 256, 256, 0, stream>>>((const float4*)y, scale, shift,
                                                        (float4*)d_out, N * 32);
}